// Round 4
// baseline (409.570 us; speedup 1.0000x reference)
//
#include <hip/hip_runtime.h>
#include <cstdint>
#include <cstddef>

#define BB 16
#define PP 19248
#define NOBJ 32
#define NCLS 81
#define POS_TH 0.5f
#define NEG_TH 0.4f
#define VAR0 0.1f
#define VAR1 0.2f
#define NEGPOS 3

// ---------------- match: per-prior best gt + per-gt best prior ----------------
__global__ __launch_bounds__(256) void k_match(const float* __restrict__ priors,
                                               const float* __restrict__ gt_boxes,
                                               unsigned long long* __restrict__ gkey,
                                               float* __restrict__ bto,
                                               int* __restrict__ bti) {
    const int b = blockIdx.y;
    const int p = blockIdx.x * 256 + threadIdx.x;
    __shared__ float sg[NOBJ * 4];
    if (threadIdx.x < NOBJ * 4) sg[threadIdx.x] = gt_boxes[b * NOBJ * 4 + threadIdx.x];
    __syncthreads();

    const bool valid = p < PP;
    float px1 = 0.f, py1 = 0.f, px2 = 0.f, py2 = 0.f, parea = 0.f;
    if (valid) {
        float4 pr = ((const float4*)priors)[p];
        float hw = pr.z / 2.0f, hh = pr.w / 2.0f;
        px1 = pr.x - hw; py1 = pr.y - hh; px2 = pr.x + hw; py2 = pr.y + hh;
        parea = (px2 - px1) * (py2 - py1);
    }

    float best_ov = -1.0f;
    int best_n = 0;
    const int lane = threadIdx.x & 63;

    for (int n = 0; n < NOBJ; ++n) {
        float gx1 = sg[n * 4 + 0], gy1 = sg[n * 4 + 1];
        float gx2 = sg[n * 4 + 2], gy2 = sg[n * 4 + 3];
        float iou = 0.0f;
        if (valid) {
#pragma clang fp contract(off)
            float ix1 = fmaxf(gx1, px1), iy1 = fmaxf(gy1, py1);
            float ix2 = fminf(gx2, px2), iy2 = fminf(gy2, py2);
            float iw = fmaxf(ix2 - ix1, 0.0f), ih = fmaxf(iy2 - iy1, 0.0f);
            float inter = iw * ih;
            float garea = (gx2 - gx1) * (gy2 - gy1);
            iou = inter / (garea + parea - inter);
        }
        if (iou > best_ov) { best_ov = iou; best_n = n; }

        // 32-bit butterfly max, then ballot to find the lowest lane holding it
        float rv = valid ? iou : -1.0f;
        float m = rv;
        m = fmaxf(m, __shfl_xor(m, 1, 64));
        m = fmaxf(m, __shfl_xor(m, 2, 64));
        m = fmaxf(m, __shfl_xor(m, 4, 64));
        m = fmaxf(m, __shfl_xor(m, 8, 64));
        m = fmaxf(m, __shfl_xor(m, 16, 64));
        m = fmaxf(m, __shfl_xor(m, 32, 64));
        if (m >= 0.0f) {
            unsigned long long ball = __ballot(rv == m);
            if (lane == 0) {
                int src = (int)__builtin_ctzll(ball);       // lowest lane = lowest p
                unsigned psrc = (unsigned)(p + src);        // lane0: p is wave base
                unsigned long long key =
                    (((unsigned long long)__float_as_uint(m)) << 32) |
                    (unsigned long long)(0xFFFFFFFFu - psrc);
                atomicMax(&gkey[b * NOBJ + n], key);
            }
        }
    }

    if (valid) {
        bto[(size_t)b * PP + p] = best_ov;
        bti[(size_t)b * PP + p] = best_n;
    }
}

// ---------------- force: sequential last-wins scatter ----------------
__global__ void k_force(const unsigned long long* __restrict__ gkey,
                        float* __restrict__ bto, int* __restrict__ bti) {
    int b = threadIdx.x;
    if (b >= BB) return;
    for (int n = 0; n < NOBJ; ++n) {
        unsigned long long key = gkey[b * NOBJ + n];
        unsigned p = 0xFFFFFFFFu - (unsigned)(key & 0xFFFFFFFFull);
        bto[(size_t)b * PP + p] = 2.0f;
        bti[(size_t)b * PP + p] = n;
    }
}

__device__ __forceinline__ float sl1(float d) {
    float ad = fabsf(d);
    return ad < 1.0f ? 0.5f * d * d : ad - 0.5f;
}

// ---------------- main: coalesced float4 -> LDS tile, quad-per-row softmax ----------------
// 64 rows x 81 classes = 20736 B LDS -> 7 blocks/CU. Staging is fully
// coalesced; the strided per-quad reads hit LDS (2-way aliasing worst case = free).
#define TMAIN 256
#define RPB 64   // rows per block (4 waves x 16 rows)
__global__ __launch_bounds__(TMAIN) void k_main(const float* __restrict__ loc_data,
                                                const float* __restrict__ conf_data,
                                                const float* __restrict__ priors,
                                                const float* __restrict__ gt_boxes,
                                                const int* __restrict__ gt_labels,
                                                const float* __restrict__ bto,
                                                const int* __restrict__ bti,
                                                float* __restrict__ mine,
                                                int* __restrict__ n_pos,
                                                float* __restrict__ acc) {
    const int b = blockIdx.y;
    const int p0 = blockIdx.x * RPB;
    __shared__ __align__(16) float sconf[RPB * NCLS];

    const int rows = min(RPB, PP - p0);
    const float4* src = (const float4*)(conf_data + ((size_t)b * PP + p0) * NCLS);
    const int nv4 = rows * NCLS / 4;   // 64*81/4=1296 or 48*81/4=972, both exact
    for (int i = threadIdx.x; i < nv4; i += TMAIN)
        ((float4*)sconf)[i] = src[i];
    __syncthreads();

    const int tid = threadIdx.x;
    const int wid = tid >> 6, lane = tid & 63;
    const int g = lane >> 2, sub = lane & 3;
    const int rl = wid * 16 + g;        // local row
    const int r = p0 + rl;              // global prior index
    const bool valid = r < PP;
    const float* row = sconf + rl * NCLS;

    float v[20];
    float v80 = -1e30f;
    if (valid) {
#pragma unroll
        for (int s = 0; s < 20; ++s) v[s] = row[sub + 4 * s];
        if (sub == 0) v80 = row[80];
    } else {
#pragma unroll
        for (int s = 0; s < 20; ++s) v[s] = -1e30f;
    }

    float m = v80;
#pragma unroll
    for (int s = 0; s < 20; ++s) m = fmaxf(m, v[s]);
    m = fmaxf(m, __shfl_xor(m, 1, 64));
    m = fmaxf(m, __shfl_xor(m, 2, 64));

    float sum = expf(v80 - m);   // 0 for sub != 0
#pragma unroll
    for (int s = 0; s < 20; ++s) sum += expf(v[s] - m);
    sum += __shfl_xor(sum, 1, 64);
    sum += __shfl_xor(sum, 2, 64);
    const float lse = m + logf(sum);

    float my_ll = 0.0f, my_lc = 0.0f;
    int my_pos = 0;

    if (valid && sub == 0) {
        float ov = bto[(size_t)b * PP + r];
        int ti = bti[(size_t)b * PP + r];
        int conf = gt_labels[b * NOBJ + ti] + 1;
        if (ov < POS_TH) conf = -1;
        if (ov < NEG_TH) conf = 0;
        int ct = conf > 0 ? conf : 0;
        float nll = lse - row[ct];

        if (conf > 0) {
            my_pos = 1;
            my_lc = nll;
            float4 gbox = ((const float4*)gt_boxes)[b * NOBJ + ti];
            float4 pr = ((const float4*)priors)[r];
            float mcx = (gbox.x + gbox.z) / 2.0f, mcy = (gbox.y + gbox.w) / 2.0f;
            float mw = gbox.z - gbox.x, mh = gbox.w - gbox.y;
            float t0 = (mcx - pr.x) / (VAR0 * pr.z);
            float t1 = (mcy - pr.y) / (VAR0 * pr.w);
            float t2 = logf(mw / pr.z) / VAR1;
            float t3 = logf(mh / pr.w) / VAR1;
            float4 ld = ((const float4*)loc_data)[(size_t)b * PP + r];
            my_ll = sl1(ld.x - t0) + sl1(ld.y - t1) + sl1(ld.z - t2) + sl1(ld.w - t3);
        }
        mine[(size_t)b * PP + r] = (conf == 0) ? nll : 0.0f;
    }

    for (int off = 32; off > 0; off >>= 1) {
        my_ll += __shfl_down(my_ll, off, 64);
        my_lc += __shfl_down(my_lc, off, 64);
        my_pos += __shfl_down(my_pos, off, 64);
    }
    __shared__ float r_ll[4], r_lc[4];
    __shared__ int r_pos[4];
    if (lane == 0) { r_ll[wid] = my_ll; r_lc[wid] = my_lc; r_pos[wid] = my_pos; }
    __syncthreads();
    if (tid == 0) {
        float ll = 0.0f, lc = 0.0f;
        int np = 0;
        for (int w = 0; w < 4; ++w) { ll += r_ll[w]; lc += r_lc[w]; np += r_pos[w]; }
        if (ll != 0.0f) atomicAdd(&acc[0], ll);
        if (lc != 0.0f) atomicAdd(&acc[1], lc);
        if (np) atomicAdd(&n_pos[b], np);
    }
}

// ---------------- select: radix top-k via ballot counting + fused finalize ----------------
#define ST 1024
__global__ __launch_bounds__(ST) void k_select(const float* __restrict__ mine,
                                               const int* __restrict__ n_pos,
                                               float* __restrict__ acc,
                                               unsigned* __restrict__ done,
                                               float* __restrict__ out) {
    const int b = blockIdx.x;
    const float* mv = mine + (size_t)b * PP;
    const int k = min(NEGPOS * n_pos[b], PP - 1);

    const int tid = threadIdx.x;
    const int wid = tid >> 6, lane = tid & 63;
    constexpr int NW = ST / 64;

    if (k > 0) {
        __shared__ unsigned swh[NW * 16];
        __shared__ unsigned stot[16];
        __shared__ unsigned s_prefix;
        __shared__ int s_rem;
        if (tid == 0) { s_prefix = 0u; s_rem = k; }
        __syncthreads();

        for (int pass = 0; pass < 8; ++pass) {
            const int shift = 28 - 4 * pass;
            const unsigned hm = (pass == 0) ? 0u : (0xFFFFFFFFu << (shift + 4));
            const unsigned prefix = s_prefix;

            unsigned cnt[16];
#pragma unroll
            for (int v = 0; v < 16; ++v) cnt[v] = 0u;

            for (int i = tid; i < PP; i += ST) {
                unsigned bits = __float_as_uint(mv[i]);
                unsigned key = ((bits & hm) == prefix) ? ((bits >> shift) & 15u) : 16u;
#pragma unroll
                for (int v = 0; v < 16; ++v)
                    cnt[v] += (unsigned)__popcll(__ballot(key == (unsigned)v));
            }
            if (lane == 0) {
#pragma unroll
                for (int v = 0; v < 16; ++v) swh[wid * 16 + v] = cnt[v];
            }
            __syncthreads();
            if (tid < 16) {
                unsigned t = 0;
#pragma unroll
                for (int w = 0; w < NW; ++w) t += swh[w * 16 + tid];
                stot[tid] = t;
            }
            __syncthreads();
            if (tid == 0) {
                int rem = s_rem;
                unsigned cum = 0;
                int chosen = 0;
                for (int v = 15; v >= 0; --v) {
                    unsigned c = stot[v];
                    if (cum + c >= (unsigned)rem) { chosen = v; s_rem = rem - (int)cum; break; }
                    cum += c;
                }
                s_prefix = prefix | ((unsigned)chosen << shift);
            }
            __syncthreads();
        }

        const unsigned T = s_prefix;
        float sum = 0.0f;
        unsigned cnt = 0;
        for (int i = tid; i < PP; i += ST) {
            float v = mv[i];
            unsigned bits = __float_as_uint(v);
            if (bits > T) { sum += v; cnt++; }
        }
        for (int off = 32; off > 0; off >>= 1) {
            sum += __shfl_down(sum, off, 64);
            cnt += __shfl_down(cnt, off, 64);
        }
        __shared__ float rs[NW];
        __shared__ unsigned rc[NW];
        if (lane == 0) { rs[wid] = sum; rc[wid] = cnt; }
        __syncthreads();
        if (tid == 0) {
            float S = 0.0f;
            int G = 0;
            for (int w = 0; w < NW; ++w) { S += rs[w]; G += (int)rc[w]; }
            float neg = S + (float)(k - G) * __uint_as_float(T);
            atomicAdd(&acc[1], neg);
        }
        __syncthreads();
    }

    // fused finalize: last block to finish writes the output
    if (tid == 0) {
        __threadfence();
        unsigned prev = atomicAdd(done, 1u);
        if (prev == BB - 1) {
            int tp = 0;
            for (int bb = 0; bb < BB; ++bb) tp += n_pos[bb];
            float N = (float)max(tp, 1);
            float a0 = atomicAdd(&acc[0], 0.0f);   // device-coherent reads
            float a1 = atomicAdd(&acc[1], 0.0f);
            out[0] = a0 / N;
            out[1] = a1 / N;
        }
    }
}

extern "C" void kernel_launch(void* const* d_in, const int* in_sizes, int n_in,
                              void* d_out, int out_size, void* d_ws, size_t ws_size,
                              hipStream_t stream) {
    const float* loc    = (const float*)d_in[0];
    const float* conf   = (const float*)d_in[1];
    const float* priors = (const float*)d_in[2];
    const float* gt     = (const float*)d_in[3];
    const int*   labels = (const int*)d_in[4];
    float* out = (float*)d_out;

    char* ws = (char*)d_ws;
    const size_t SZ_BP = (size_t)BB * PP * 4;  // 1,231,872 B
    // [0,4096) gkey | [4096,4160) npos | [4160,4168) acc | [4168,4172) done | pad to 4224
    unsigned long long* gkey = (unsigned long long*)ws;
    int*      npos = (int*)     (ws + 4096);
    float*    acc  = (float*)   (ws + 4160);
    unsigned* done = (unsigned*)(ws + 4168);
    float* bto  = (float*)(ws + 4224);
    int*   bti  = (int*)  (ws + 4224 + SZ_BP);
    float* mine = (float*)(ws + 4224 + 2 * SZ_BP);

    hipMemsetAsync(ws, 0, 4224, stream);

    dim3 mg((PP + 255) / 256, BB);
    k_match<<<mg, 256, 0, stream>>>(priors, gt, gkey, bto, bti);

    k_force<<<1, 64, 0, stream>>>(gkey, bto, bti);

    dim3 mg2((PP + RPB - 1) / RPB, BB);
    k_main<<<mg2, TMAIN, 0, stream>>>(loc, conf, priors, gt, labels, bto, bti, mine, npos, acc);

    k_select<<<BB, ST, 0, stream>>>(mine, npos, acc, done, out);
}